// Round 1
// baseline (1025.234 us; speedup 1.0000x reference)
//
#include <hip/hip_runtime.h>
#include <hip/hip_bf16.h>

// nh[n][t] = sum_k x[n][k] * v[k][t]
__global__ __launch_bounds__(256) void nh_kernel(const float* __restrict__ x,
                                                 const float* __restrict__ v,
                                                 float* __restrict__ nh, int N) {
  int gid = blockIdx.x * 256 + threadIdx.x;
  if (gid >= N * 32) return;
  int n = gid >> 5, t = gid & 31;
  float x0 = x[3 * n], x1 = x[3 * n + 1], x2 = x[3 * n + 2];
  nh[gid] = fmaf(x0, v[t], fmaf(x1, v[32 + t], x2 * v[64 + t]));
}

// One thread per simplex (node / edge / face). Each thread evaluates the
// 32x32 (bump, theta) sigmoid grid and accumulates sign * sigmoid into a
// block-private LDS histogram [8 graphs][32 bump][32 theta], then flushes
// via global f32 atomics.
__global__ __launch_bounds__(256) void ecc_kernel(
    const float* __restrict__ nh, const int* __restrict__ ei,
    const int* __restrict__ face, const int* __restrict__ batch,
    const float* __restrict__ lin, const int* __restrict__ scale_p,
    float* __restrict__ acc_g, int N, int E, int F) {
  __shared__ float acc[8 * 1024];
  __shared__ float lin_s[32];
  const int tid = threadIdx.x;
  for (int i = tid; i < 8 * 1024; i += 256) acc[i] = 0.f;
  if (tid < 32) lin_s[tid] = lin[tid];
  __syncthreads();

  const int M = N + E + F;
  const int m = blockIdx.x * 256 + tid;
  const float scale = (float)scale_p[0];

  float h[32];
  int g = 0;
  float sign = 1.f;
  const bool active = (m < M);
  if (active) {
    if (m < N) {  // node
      const float4* r0 = (const float4*)(nh + (size_t)m * 32);
#pragma unroll
      for (int i = 0; i < 8; ++i) {
        float4 a = r0[i];
        h[4 * i] = a.x; h[4 * i + 1] = a.y; h[4 * i + 2] = a.z; h[4 * i + 3] = a.w;
      }
      g = batch[m];
      sign = 1.f;
    } else if (m < N + E) {  // edge: max over 2 endpoints, sign -1
      int e = m - N;
      int n0 = ei[e], n1 = ei[E + e];
      const float4* r0 = (const float4*)(nh + (size_t)n0 * 32);
      const float4* r1 = (const float4*)(nh + (size_t)n1 * 32);
#pragma unroll
      for (int i = 0; i < 8; ++i) {
        float4 a = r0[i], b = r1[i];
        h[4 * i]     = fmaxf(a.x, b.x);
        h[4 * i + 1] = fmaxf(a.y, b.y);
        h[4 * i + 2] = fmaxf(a.z, b.z);
        h[4 * i + 3] = fmaxf(a.w, b.w);
      }
      g = batch[n0];
      sign = -1.f;
    } else {  // face: max over 3 vertices, sign +1
      int f = m - N - E;
      int n0 = face[f], n1 = face[F + f], n2 = face[2 * F + f];
      const float4* r0 = (const float4*)(nh + (size_t)n0 * 32);
      const float4* r1 = (const float4*)(nh + (size_t)n1 * 32);
      const float4* r2 = (const float4*)(nh + (size_t)n2 * 32);
#pragma unroll
      for (int i = 0; i < 8; ++i) {
        float4 a = r0[i], b = r1[i], c = r2[i];
        h[4 * i]     = fmaxf(fmaxf(a.x, b.x), c.x);
        h[4 * i + 1] = fmaxf(fmaxf(a.y, b.y), c.y);
        h[4 * i + 2] = fmaxf(fmaxf(a.z, b.z), c.z);
        h[4 * i + 3] = fmaxf(fmaxf(a.w, b.w), c.w);
      }
      g = batch[n0];
      sign = 1.f;
    }
  }

  if (active) {
    const int lane = tid & 63;
    const int hi16 = (lane >= 32) ? 16 : 0;  // upper half-wave walks theta^16
    const int lb = lane & 31;
    // Pre-swap h halves for upper lanes: after this, h[t] holds the height of
    // logical theta (t ^ hi16). One-time 32 cndmasks instead of per-iteration.
#pragma unroll
    for (int t = 0; t < 16; ++t) {
      float lo = h[t], hv = h[t + 16];
      h[t]      = hi16 ? hv : lo;
      h[t + 16] = hi16 ? lo : hv;
    }
    const int gbase = g << 10;
    for (int bb = 0; bb < 32; ++bb) {
      int b = (bb + lb) & 31;        // per-lane bump offset -> distinct banks
      float linb = lin_s[b];
      int base2 = gbase + (b << 5);
      int mx = hi16 ^ b;             // theta-swizzle: phys_t = logical_t ^ b
#pragma unroll
      for (int t = 0; t < 32; ++t) {
        float s = scale * (linb - h[t]);
        float e = __expf(-s);                       // s>>0 -> e=0 -> val=sign
        float val = sign * __builtin_amdgcn_rcpf(1.0f + e);  // s<<0 -> e=inf -> 0
        __hip_atomic_fetch_add(&acc[base2 + (t ^ mx)], val,
                               __ATOMIC_RELAXED, __HIP_MEMORY_SCOPE_WORKGROUP);
      }
    }
  }
  __syncthreads();

  // Flush block-private histogram: logical (g,b,t) lives at phys t-index t^b.
  for (int i = tid; i < 8 * 1024; i += 256) {
    int b = (i >> 5) & 31;
    float vv = acc[(i & ~31) | ((i & 31) ^ b)];
    if (vv != 0.f)
      __hip_atomic_fetch_add(&acc_g[i], vv, __ATOMIC_RELAXED,
                             __HIP_MEMORY_SCOPE_AGENT);
  }
}

// One block per graph: per-graph max over [32][32], then normalize.
__global__ __launch_bounds__(1024) void fin_kernel(const float* __restrict__ acc_g,
                                                   float* __restrict__ out) {
  int g = blockIdx.x, tid = threadIdx.x;
  float v = acc_g[(g << 10) + tid];
  float m = v;
#pragma unroll
  for (int off = 32; off > 0; off >>= 1) m = fmaxf(m, __shfl_down(m, off));
  __shared__ float wmax[16];
  if ((tid & 63) == 0) wmax[tid >> 6] = m;
  __syncthreads();
  if (tid == 0) {
    float mm = wmax[0];
#pragma unroll
    for (int w = 1; w < 16; ++w) mm = fmaxf(mm, wmax[w]);
    wmax[0] = mm;
  }
  __syncthreads();
  out[(g << 10) + tid] = v / wmax[0];
}

extern "C" void kernel_launch(void* const* d_in, const int* in_sizes, int n_in,
                              void* d_out, int out_size, void* d_ws, size_t ws_size,
                              hipStream_t stream) {
  const float* x     = (const float*)d_in[0];
  const float* v     = (const float*)d_in[1];
  const float* lin   = (const float*)d_in[2];
  const int*   ei    = (const int*)d_in[3];
  const int*   face  = (const int*)d_in[4];
  const int*   batch = (const int*)d_in[5];
  const int*   scale = (const int*)d_in[6];
  const int N = in_sizes[5];
  const int E = in_sizes[3] / 2;
  const int F = in_sizes[4] / 3;

  float* acc_g = (float*)d_ws;        // [8*1024] global accumulator
  float* nh    = acc_g + 8 * 1024;    // [N*32] node heights

  hipMemsetAsync(d_ws, 0, 8 * 1024 * sizeof(float), stream);
  nh_kernel<<<(N * 32 + 255) / 256, 256, 0, stream>>>(x, v, nh, N);

  const int M = N + E + F;
  ecc_kernel<<<(M + 255) / 256, 256, 0, stream>>>(nh, ei, face, batch, lin,
                                                  scale, acc_g, N, E, F);

  const int B = out_size / 1024;
  fin_kernel<<<B, 1024, 0, stream>>>(acc_g, (float*)d_out);
}

// Round 2
// 98.725 us; speedup vs baseline: 10.3847x; 10.3847x over previous
//
#include <hip/hip_runtime.h>
#include <math.h>

#define CHUNK 256   // simplices per ecc block
#define SB 32       // sub-batch staged in LDS

// K1: nh[n][t] = x[n] . v[:,t]
__global__ __launch_bounds__(256) void nh_kernel(const float* __restrict__ x,
                                                 const float* __restrict__ v,
                                                 float* __restrict__ nh, int N) {
  int gid = blockIdx.x * 256 + threadIdx.x;
  if (gid >= N * 32) return;
  int n = gid >> 5, t = gid & 31;
  nh[gid] = fmaf(x[3 * n], v[t], fmaf(x[3 * n + 1], v[32 + t], x[3 * n + 2] * v[64 + t]));
}

__device__ __forceinline__ int graph_of(int m, const int* __restrict__ ei,
                                        const int* __restrict__ face,
                                        const int* __restrict__ batch,
                                        int N, int E, int F) {
  if (m < N) return batch[m];
  if (m < N + E) return batch[ei[m - N]];
  return batch[face[m - N - E]];
}

// K2: per-block histogram of graph ids (int LDS atomics only — hardware)
__global__ __launch_bounds__(256) void count_kernel(const int* __restrict__ ei,
    const int* __restrict__ face, const int* __restrict__ batch,
    int* __restrict__ bhist, int N, int E, int F) {
  __shared__ int hist[8];
  int tid = threadIdx.x;
  if (tid < 8) hist[tid] = 0;
  __syncthreads();
  int m = blockIdx.x * 256 + tid;
  if (m < N + E + F)
    atomicAdd(&hist[graph_of(m, ei, face, batch, N, E, F)], 1);
  __syncthreads();
  if (tid < 8) bhist[blockIdx.x * 8 + tid] = hist[tid];
}

// K3: single-block scan: per-graph totals, graph bases, chunk offsets, and
// per-(block,graph) scatter bases. meta: [0..8)=counts [8..16)=gbase
// [16..25)=chunkoff (chunkoff[8]=total chunks at meta[24])
__global__ __launch_bounds__(256) void scan_kernel(const int* __restrict__ bhist,
    int* __restrict__ base, int* __restrict__ meta, int NB) {
  __shared__ int h[768 * 8];
  __shared__ int psum[8][33];
  __shared__ int gb_s[8];
  int tid = threadIdx.x;
  for (int i = tid; i < NB * 8; i += 256) h[i] = bhist[i];
  __syncthreads();
  int g = tid >> 5, j = tid & 31;
  int per = (NB + 31) / 32;
  int b0 = j * per, b1 = min(b0 + per, NB);
  int s = 0;
  for (int b = b0; b < b1; ++b) s += h[b * 8 + g];
  psum[g][j] = s;
  __syncthreads();
  if (j == 0) {
    int run = 0;
    for (int k = 0; k < 32; ++k) { int tv = psum[g][k]; psum[g][k] = run; run += tv; }
    psum[g][32] = run;
  }
  __syncthreads();
  if (tid == 0) {
    int run = 0, coff = 0;
    for (int gg = 0; gg < 8; ++gg) {
      int tv = psum[gg][32];
      meta[gg] = tv;
      meta[8 + gg] = run;
      gb_s[gg] = run;
      run += tv;
    }
    for (int gg = 0; gg < 8; ++gg) {
      meta[16 + gg] = coff;
      coff += (psum[gg][32] + CHUNK - 1) / CHUNK;
    }
    meta[24] = coff;
  }
  __syncthreads();
  int run = gb_s[g] + psum[g][j];
  for (int b = b0; b < b1; ++b) {
    base[b * 8 + g] = run;
    run += h[b * 8 + g];
  }
}

// K4: deterministic counting-sort scatter (ballot ranks, no fp atomics)
__global__ __launch_bounds__(256) void scatter_kernel(const int* __restrict__ ei,
    const int* __restrict__ face, const int* __restrict__ batch,
    const int* __restrict__ base, int* __restrict__ sorted, int N, int E, int F) {
  __shared__ int wcnt[4][8];
  __shared__ int woff[4][8];
  int tid = threadIdx.x;
  int m = blockIdx.x * 256 + tid;
  int g = -1;
  if (m < N + E + F) g = graph_of(m, ei, face, batch, N, E, F);
  int w = tid >> 6, lane = tid & 63;
  unsigned long long below = (1ull << lane) - 1ull;
  int myrank = 0;
#pragma unroll
  for (int gg = 0; gg < 8; ++gg) {
    unsigned long long mm = __ballot(g == gg);
    if (g == gg) myrank = __popcll(mm & below);
    if (lane == gg) wcnt[w][gg] = __popcll(mm);
  }
  __syncthreads();
  if (tid < 32) {
    int w2 = tid >> 3, g2 = tid & 7;
    int o = 0;
    for (int ww = 0; ww < w2; ++ww) o += wcnt[ww][g2];
    woff[w2][g2] = o;
  }
  __syncthreads();
  if (g >= 0)
    sorted[base[blockIdx.x * 8 + g] + woff[w][g] + myrank] = m;
}

// K5: the hot kernel. Block = one chunk of one graph. Thread (b,t) register-
// accumulates its (bump,theta) cell over the chunk's simplices. Heights
// double-buffered in LDS [t][s] rows of stride 36 (16B-aligned b128 reads).
__global__ __launch_bounds__(1024) void ecc_kernel(const float* __restrict__ nh,
    const int* __restrict__ ei, const int* __restrict__ face,
    const int* __restrict__ sorted, const int* __restrict__ meta,
    const float* __restrict__ lin, const int* __restrict__ scale_p,
    float* __restrict__ partial, int N, int E, int F) {
  __shared__ float hbuf[2][32][36];
  __shared__ float sgbuf[2][36];
  int bid = blockIdx.x;
  if (bid >= meta[24]) return;
  int g = 0;
#pragma unroll
  for (int gg = 1; gg < 8; ++gg) if (bid >= meta[16 + gg]) g = gg;
  int c = bid - meta[16 + g];
  int cnt = meta[g];
  int start = meta[8 + g] + c * CHUNK;
  int nrem = min(CHUNK, cnt - c * CHUNK);
  int tid = threadIdx.x;
  int t = tid & 31, b = tid >> 5;   // b doubles as the stager's s-slot
  float A2 = (float)scale_p[0] * 1.44269504088896340736f;  // scale*log2(e)
  float B2 = -lin[b] * A2;
  float acc = 0.f;
  int nsb = (nrem + SB - 1) / SB;

  auto stage = [&](int i, int buf) {
    int idx = i * SB + b;
    float h = INFINITY, sn = 0.f;   // +INF -> sigmoid contribution exactly 0
    if (idx < nrem) {
      int m = sorted[start + idx];
      if (m < N) {
        h = nh[(size_t)m * 32 + t];
        sn = 1.f;
      } else if (m < N + E) {
        int e = m - N;
        h = fmaxf(nh[(size_t)ei[e] * 32 + t], nh[(size_t)ei[E + e] * 32 + t]);
        sn = -1.f;
      } else {
        int f = m - N - E;
        h = fmaxf(fmaxf(nh[(size_t)face[f] * 32 + t],
                        nh[(size_t)face[F + f] * 32 + t]),
                  nh[(size_t)face[2 * F + f] * 32 + t]);
        sn = 1.f;
      }
    }
    hbuf[buf][t][b] = h;
    if (t == 0) sgbuf[buf][b] = sn;
  };

  stage(0, 0);
  __syncthreads();
  for (int i = 0; i < nsb; ++i) {
    int cur = i & 1;
    if (i + 1 < nsb) stage(i + 1, cur ^ 1);  // global gathers overlap compute
#pragma unroll
    for (int so = 0; so < 8; ++so) {
      float4 hv = *(const float4*)&hbuf[cur][t][so * 4];
      float4 sv = *(const float4*)&sgbuf[cur][so * 4];  // broadcast
      acc = fmaf(sv.x, __builtin_amdgcn_rcpf(1.f + __builtin_amdgcn_exp2f(fmaf(hv.x, A2, B2))), acc);
      acc = fmaf(sv.y, __builtin_amdgcn_rcpf(1.f + __builtin_amdgcn_exp2f(fmaf(hv.y, A2, B2))), acc);
      acc = fmaf(sv.z, __builtin_amdgcn_rcpf(1.f + __builtin_amdgcn_exp2f(fmaf(hv.z, A2, B2))), acc);
      acc = fmaf(sv.w, __builtin_amdgcn_rcpf(1.f + __builtin_amdgcn_exp2f(fmaf(hv.w, A2, B2))), acc);
    }
    __syncthreads();
  }
  partial[(size_t)bid * 1024 + tid] = acc;
}

// K6: per-graph reduction over chunk partials, max-normalize, write out
__global__ __launch_bounds__(1024) void fin_kernel(const float* __restrict__ partial,
    const int* __restrict__ meta, float* __restrict__ out) {
  int g = blockIdx.x, tid = threadIdx.x;
  int nch = (meta[g] + CHUNK - 1) / CHUNK;
  int pbase = meta[16 + g];
  float acc = 0.f;
  for (int c = 0; c < nch; ++c)
    acc += partial[(size_t)(pbase + c) * 1024 + tid];
  float m = acc;
#pragma unroll
  for (int off = 32; off > 0; off >>= 1) m = fmaxf(m, __shfl_down(m, off));
  __shared__ float wmax[16];
  if ((tid & 63) == 0) wmax[tid >> 6] = m;
  __syncthreads();
  if (tid == 0) {
    float mm = wmax[0];
#pragma unroll
    for (int w = 1; w < 16; ++w) mm = fmaxf(mm, wmax[w]);
    wmax[0] = mm;
  }
  __syncthreads();
  out[(size_t)g * 1024 + tid] = acc / wmax[0];
}

extern "C" void kernel_launch(void* const* d_in, const int* in_sizes, int n_in,
                              void* d_out, int out_size, void* d_ws, size_t ws_size,
                              hipStream_t stream) {
  const float* x     = (const float*)d_in[0];
  const float* v     = (const float*)d_in[1];
  const float* lin   = (const float*)d_in[2];
  const int*   ei    = (const int*)d_in[3];
  const int*   face  = (const int*)d_in[4];
  const int*   batch = (const int*)d_in[5];
  const int*   scale = (const int*)d_in[6];
  const int N = in_sizes[5];
  const int E = in_sizes[3] / 2;
  const int F = in_sizes[4] / 3;
  const int M = N + E + F;
  const int NB = (M + 255) / 256;

  float* nh      = (float*)d_ws;                 // N*32 f32
  int*   sorted  = (int*)(nh + (size_t)N * 32);  // M ints
  int*   bhist   = sorted + M;                   // NB*8
  int*   base    = bhist + (size_t)NB * 8;       // NB*8
  int*   meta    = base + (size_t)NB * 8;        // 32
  float* partial = (float*)(meta + 32);          // (ceil(M/CHUNK)+8)*1024 f32

  nh_kernel<<<(N * 32 + 255) / 256, 256, 0, stream>>>(x, v, nh, N);
  count_kernel<<<NB, 256, 0, stream>>>(ei, face, batch, bhist, N, E, F);
  scan_kernel<<<1, 256, 0, stream>>>(bhist, base, meta, NB);
  scatter_kernel<<<NB, 256, 0, stream>>>(ei, face, batch, base, sorted, N, E, F);
  const int grid_ecc = (M + CHUNK - 1) / CHUNK + 8;
  ecc_kernel<<<grid_ecc, 1024, 0, stream>>>(nh, ei, face, sorted, meta, lin,
                                            scale, partial, N, E, F);
  fin_kernel<<<8, 1024, 0, stream>>>(partial, meta, (float*)d_out);
}

// Round 3
// 91.101 us; speedup vs baseline: 11.2539x; 1.0837x over previous
//
#include <hip/hip_runtime.h>
#include <math.h>

#define CHUNK 128   // simplices per ect block

// K1: nh[n][t] = x[n].v[:,t]; blocks < NB also histogram graph ids.
__global__ __launch_bounds__(256) void nh_count_kernel(
    const float* __restrict__ x, const float* __restrict__ v,
    float* __restrict__ nh, const int* __restrict__ ei,
    const int* __restrict__ face, const int* __restrict__ batch,
    int* __restrict__ bhist, int N, int E, int F, int NB) {
  int tid = threadIdx.x;
  int gid = blockIdx.x * 256 + tid;
  if (gid < N * 32) {
    int n = gid >> 5, t = gid & 31;
    nh[gid] = fmaf(x[3 * n], v[t], fmaf(x[3 * n + 1], v[32 + t], x[3 * n + 2] * v[64 + t]));
  }
  if (blockIdx.x < (unsigned)NB) {
    __shared__ int hist[8];
    if (tid < 8) hist[tid] = 0;
    __syncthreads();
    int m = blockIdx.x * 256 + tid;
    if (m < N + E + F) {
      int g;
      if (m < N) g = batch[m];
      else if (m < N + E) g = batch[ei[m - N]];
      else g = batch[face[m - N - E]];
      atomicAdd(&hist[g], 1);
    }
    __syncthreads();
    if (tid < 8) bhist[blockIdx.x * 8 + tid] = hist[tid];
  }
}

// K2: single-block scan -> per-graph totals/bases, chunk offsets, scatter bases
// meta: [0..8)=counts [8..16)=gbase [16..24)=chunkoff [24]=total chunks
__global__ __launch_bounds__(256) void scan_kernel(const int* __restrict__ bhist,
    int* __restrict__ base, int* __restrict__ meta, int NB) {
  __shared__ int h[768 * 8];
  __shared__ int psum[8][33];
  __shared__ int gb_s[8];
  int tid = threadIdx.x;
  for (int i = tid; i < NB * 8; i += 256) h[i] = bhist[i];
  __syncthreads();
  int g = tid >> 5, j = tid & 31;
  int per = (NB + 31) / 32;
  int b0 = j * per, b1 = min(b0 + per, NB);
  int s = 0;
  for (int b = b0; b < b1; ++b) s += h[b * 8 + g];
  psum[g][j] = s;
  __syncthreads();
  if (j == 0) {
    int run = 0;
    for (int k = 0; k < 32; ++k) { int tv = psum[g][k]; psum[g][k] = run; run += tv; }
    psum[g][32] = run;
  }
  __syncthreads();
  if (tid == 0) {
    int run = 0, coff = 0;
    for (int gg = 0; gg < 8; ++gg) {
      int tv = psum[gg][32];
      meta[gg] = tv;
      meta[8 + gg] = run;
      gb_s[gg] = run;
      run += tv;
    }
    for (int gg = 0; gg < 8; ++gg) {
      meta[16 + gg] = coff;
      coff += (psum[gg][32] + CHUNK - 1) / CHUNK;
    }
    meta[24] = coff;
  }
  __syncthreads();
  int run = gb_s[g] + psum[g][j];
  for (int b = b0; b < b1; ++b) {
    base[b * 8 + g] = run;
    run += h[b * 8 + g];
  }
}

// K3: deterministic counting-sort scatter (ballot ranks)
__global__ __launch_bounds__(256) void scatter_kernel(const int* __restrict__ ei,
    const int* __restrict__ face, const int* __restrict__ batch,
    const int* __restrict__ base, int* __restrict__ sorted, int N, int E, int F) {
  __shared__ int wcnt[4][8];
  __shared__ int woff[4][8];
  int tid = threadIdx.x;
  int m = blockIdx.x * 256 + tid;
  int g = -1;
  if (m < N + E + F) {
    if (m < N) g = batch[m];
    else if (m < N + E) g = batch[ei[m - N]];
    else g = batch[face[m - N - E]];
  }
  int w = tid >> 6, lane = tid & 63;
  unsigned long long below = (1ull << lane) - 1ull;
  int myrank = 0;
#pragma unroll
  for (int gg = 0; gg < 8; ++gg) {
    unsigned long long mm = __ballot(g == gg);
    if (g == gg) myrank = __popcll(mm & below);
    if (lane == gg) wcnt[w][gg] = __popcll(mm);
  }
  __syncthreads();
  if (tid < 32) {
    int w2 = tid >> 3, g2 = tid & 7;
    int o = 0;
    for (int ww = 0; ww < w2; ++ww) o += wcnt[ww][g2];
    woff[w2][g2] = o;
  }
  __syncthreads();
  if (g >= 0)
    sorted[base[blockIdx.x * 8 + g] + woff[w][g] + myrank] = m;
}

// K4: saturation-split ECT. Per (simplex,theta): sigmoid only for the <=2
// transition bins (fixed-point LDS atomics); the saturated "all ones above"
// region is an exact int count, prefix-summed per block.
__global__ __launch_bounds__(256) void ect_kernel(const float* __restrict__ nh,
    const int* __restrict__ ei, const int* __restrict__ face,
    const int* __restrict__ sorted, const int* __restrict__ meta,
    const float* __restrict__ lin, const int* __restrict__ scale_p,
    float* __restrict__ partial, int N, int E, int F) {
  __shared__ int acc[32][32];   // fixed-point 2^20 transition sums [b][t]
  __shared__ int cnt[32][32];   // full-region start markers [k][t]
  int bid = blockIdx.x;
  if (bid >= meta[24]) return;
  int g = 0;
#pragma unroll
  for (int gg = 1; gg < 8; ++gg) if (bid >= meta[16 + gg]) g = gg;
  int c = bid - meta[16 + g];
  int total = meta[g];
  int start = meta[8 + g] + c * CHUNK;
  int nrem = min(CHUNK, total - c * CHUNK);
  int tid = threadIdx.x;
  int t = tid & 31, srow = tid >> 5;
  for (int i = tid; i < 1024; i += 256) { ((int*)acc)[i] = 0; ((int*)cnt)[i] = 0; }
  __syncthreads();

  float scale = (float)scale_p[0];
  float lin0 = lin[0];
  float step = (lin[31] - lin0) * (1.f / 31.f);
  float istep = 1.f / step;
  float Cl = scale * step * 1.44269504088896f;  // log2-slope per bin
  float w = 25.f / (scale * step);              // transition half-width (bins)

#pragma unroll 2
  for (int idx = srow; idx < nrem; idx += 8) {
    int m = sorted[start + idx];
    float h;
    int isn;
    if (m < N) {
      h = nh[(size_t)m * 32 + t];
      isn = 1;
    } else if (m < N + E) {
      int e = m - N;
      h = fmaxf(nh[(size_t)ei[e] * 32 + t], nh[(size_t)ei[E + e] * 32 + t]);
      isn = -1;
    } else {
      int f = m - N - E;
      h = fmaxf(fmaxf(nh[(size_t)face[f] * 32 + t],
                      nh[(size_t)face[F + f] * 32 + t]),
                nh[(size_t)face[2 * F + f] * 32 + t]);
      isn = 1;
    }
    float kf = (h - lin0) * istep;
    int b0 = (int)ceilf(kf - w);
    int b1 = (int)floorf(kf + w);
    int fs = max(b1 + 1, 0);
    if (fs <= 31) atomicAdd(&cnt[fs][t], isn);
    float q = Cl * kf;
    float fsn = (float)isn;
    int blo = max(b0, 0), bhi = min(b1, 31);
    for (int b = blo; b <= bhi; ++b) {
      float e2 = __builtin_amdgcn_exp2f(fmaf(-Cl, (float)b, q));
      float val = fsn * __builtin_amdgcn_rcpf(1.f + e2);
      atomicAdd(&acc[b][t], (int)rintf(val * 1048576.f));
    }
  }
  __syncthreads();
  if (tid < 32) {  // prefix-sum cnt over bins for theta=tid
    int run = 0;
    for (int k = 0; k < 32; ++k) { run += cnt[k][tid]; cnt[k][tid] = run; }
  }
  __syncthreads();
  for (int i = tid; i < 1024; i += 256) {
    int b = i >> 5, tt = i & 31;
    partial[(size_t)bid * 1024 + i] =
        (float)cnt[b][tt] + (float)acc[b][tt] * (1.f / 1048576.f);
  }
}

// K5: per-graph reduction over chunk partials, max-normalize
__global__ __launch_bounds__(1024) void fin_kernel(const float* __restrict__ partial,
    const int* __restrict__ meta, float* __restrict__ out) {
  int g = blockIdx.x, tid = threadIdx.x;
  int nch = (meta[g] + CHUNK - 1) / CHUNK;
  int pbase = meta[16 + g];
  float acc = 0.f;
  for (int c = 0; c < nch; ++c)
    acc += partial[(size_t)(pbase + c) * 1024 + tid];
  float m = acc;
#pragma unroll
  for (int off = 32; off > 0; off >>= 1) m = fmaxf(m, __shfl_down(m, off));
  __shared__ float wmax[16];
  if ((tid & 63) == 0) wmax[tid >> 6] = m;
  __syncthreads();
  if (tid == 0) {
    float mm = wmax[0];
#pragma unroll
    for (int ww = 1; ww < 16; ++ww) mm = fmaxf(mm, wmax[ww]);
    wmax[0] = mm;
  }
  __syncthreads();
  out[(size_t)g * 1024 + tid] = acc / wmax[0];
}

extern "C" void kernel_launch(void* const* d_in, const int* in_sizes, int n_in,
                              void* d_out, int out_size, void* d_ws, size_t ws_size,
                              hipStream_t stream) {
  const float* x     = (const float*)d_in[0];
  const float* v     = (const float*)d_in[1];
  const float* lin   = (const float*)d_in[2];
  const int*   ei    = (const int*)d_in[3];
  const int*   face  = (const int*)d_in[4];
  const int*   batch = (const int*)d_in[5];
  const int*   scale = (const int*)d_in[6];
  const int N = in_sizes[5];
  const int E = in_sizes[3] / 2;
  const int F = in_sizes[4] / 3;
  const int M = N + E + F;
  const int NB = (M + 255) / 256;

  float* nh      = (float*)d_ws;                 // N*32 f32
  int*   sorted  = (int*)(nh + (size_t)N * 32);  // M
  int*   bhist   = sorted + M;                   // NB*8
  int*   base    = bhist + (size_t)NB * 8;       // NB*8
  int*   meta    = base + (size_t)NB * 8;        // 32
  float* partial = (float*)(meta + 32);          // (M/CHUNK+8)*1024 f32

  int grid1 = max((N * 32 + 255) / 256, NB);
  nh_count_kernel<<<grid1, 256, 0, stream>>>(x, v, nh, ei, face, batch, bhist,
                                             N, E, F, NB);
  scan_kernel<<<1, 256, 0, stream>>>(bhist, base, meta, NB);
  scatter_kernel<<<NB, 256, 0, stream>>>(ei, face, batch, base, sorted, N, E, F);
  const int grid_ect = (M + CHUNK - 1) / CHUNK + 8;
  ect_kernel<<<grid_ect, 256, 0, stream>>>(nh, ei, face, sorted, meta, lin,
                                           scale, partial, N, E, F);
  fin_kernel<<<8, 1024, 0, stream>>>(partial, meta, (float*)d_out);
}

// Round 4
// 66.383 us; speedup vs baseline: 15.4443x; 1.3724x over previous
//
#include <hip/hip_runtime.h>
#include <math.h>

#define CHUNK 256   // simplices per ect block
#define RS 16       // reduction slices per graph

// K1: nh[n][t] = x[n].v[:,t]; blocks < NB also histogram graph ids.
__global__ __launch_bounds__(256) void nh_count_kernel(
    const float* __restrict__ x, const float* __restrict__ v,
    float* __restrict__ nh, const int* __restrict__ ei,
    const int* __restrict__ face, const int* __restrict__ batch,
    int* __restrict__ bhist, int N, int E, int F, int NB) {
  int tid = threadIdx.x;
  int gid = blockIdx.x * 256 + tid;
  if (gid < N * 32) {
    int n = gid >> 5, t = gid & 31;
    nh[gid] = fmaf(x[3 * n], v[t], fmaf(x[3 * n + 1], v[32 + t], x[3 * n + 2] * v[64 + t]));
  }
  if (blockIdx.x < (unsigned)NB) {
    __shared__ int hist[8];
    if (tid < 8) hist[tid] = 0;
    __syncthreads();
    int m = blockIdx.x * 256 + tid;
    if (m < N + E + F) {
      int g;
      if (m < N) g = batch[m];
      else if (m < N + E) g = batch[ei[m - N]];
      else g = batch[face[m - N - E]];
      atomicAdd(&hist[g], 1);
    }
    __syncthreads();
    if (tid < 8) bhist[blockIdx.x * 8 + tid] = hist[tid];
  }
}

// K2: single-block scan -> per-graph totals/bases, chunk offsets, scatter bases
// meta: [0..8)=counts [8..16)=gbase [16..24)=chunkoff [24]=total chunks
__global__ __launch_bounds__(256) void scan_kernel(const int* __restrict__ bhist,
    int* __restrict__ base, int* __restrict__ meta, int NB) {
  __shared__ int h[768 * 8];
  __shared__ int psum[8][33];
  __shared__ int gb_s[8];
  int tid = threadIdx.x;
  for (int i = tid; i < NB * 8; i += 256) h[i] = bhist[i];
  __syncthreads();
  int g = tid >> 5, j = tid & 31;
  int per = (NB + 31) / 32;
  int b0 = j * per, b1 = min(b0 + per, NB);
  int s = 0;
  for (int b = b0; b < b1; ++b) s += h[b * 8 + g];
  psum[g][j] = s;
  __syncthreads();
  if (j == 0) {
    int run = 0;
    for (int k = 0; k < 32; ++k) { int tv = psum[g][k]; psum[g][k] = run; run += tv; }
    psum[g][32] = run;
  }
  __syncthreads();
  if (tid == 0) {
    int run = 0, coff = 0;
    for (int gg = 0; gg < 8; ++gg) {
      int tv = psum[gg][32];
      meta[gg] = tv;
      meta[8 + gg] = run;
      gb_s[gg] = run;
      run += tv;
    }
    for (int gg = 0; gg < 8; ++gg) {
      meta[16 + gg] = coff;
      coff += (psum[gg][32] + CHUNK - 1) / CHUNK;
    }
    meta[24] = coff;
  }
  __syncthreads();
  int run = gb_s[g] + psum[g][j];
  for (int b = b0; b < b1; ++b) {
    base[b * 8 + g] = run;
    run += h[b * 8 + g];
  }
}

// K3: deterministic counting-sort scatter (ballot ranks)
__global__ __launch_bounds__(256) void scatter_kernel(const int* __restrict__ ei,
    const int* __restrict__ face, const int* __restrict__ batch,
    const int* __restrict__ base, int* __restrict__ sorted, int N, int E, int F) {
  __shared__ int wcnt[4][8];
  __shared__ int woff[4][8];
  int tid = threadIdx.x;
  int m = blockIdx.x * 256 + tid;
  int g = -1;
  if (m < N + E + F) {
    if (m < N) g = batch[m];
    else if (m < N + E) g = batch[ei[m - N]];
    else g = batch[face[m - N - E]];
  }
  int w = tid >> 6, lane = tid & 63;
  unsigned long long below = (1ull << lane) - 1ull;
  int myrank = 0;
#pragma unroll
  for (int gg = 0; gg < 8; ++gg) {
    unsigned long long mm = __ballot(g == gg);
    if (g == gg) myrank = __popcll(mm & below);
    if (lane == gg) wcnt[w][gg] = __popcll(mm);
  }
  __syncthreads();
  if (tid < 32) {
    int w2 = tid >> 3, g2 = tid & 7;
    int o = 0;
    for (int ww = 0; ww < w2; ++ww) o += wcnt[ww][g2];
    woff[w2][g2] = o;
  }
  __syncthreads();
  if (g >= 0)
    sorted[base[blockIdx.x * 8 + g] + woff[w][g] + myrank] = m;
}

// K4: saturation-split ECT. Per (simplex,theta): sigmoid only for the <=2
// transition bins (fixed-point LDS atomics); the saturated "all ones above"
// region is an exact int count, prefix-summed per block.
__global__ __launch_bounds__(256) void ect_kernel(const float* __restrict__ nh,
    const int* __restrict__ ei, const int* __restrict__ face,
    const int* __restrict__ sorted, const int* __restrict__ meta,
    const float* __restrict__ lin, const int* __restrict__ scale_p,
    float* __restrict__ partial, int N, int E, int F) {
  __shared__ int acc[32][32];   // fixed-point 2^20 transition sums [b][t]
  __shared__ int cnt[32][32];   // full-region start markers [k][t]
  int bid = blockIdx.x;
  if (bid >= meta[24]) return;
  int g = 0;
#pragma unroll
  for (int gg = 1; gg < 8; ++gg) if (bid >= meta[16 + gg]) g = gg;
  int c = bid - meta[16 + g];
  int total = meta[g];
  int start = meta[8 + g] + c * CHUNK;
  int nrem = min(CHUNK, total - c * CHUNK);
  int tid = threadIdx.x;
  int t = tid & 31, srow = tid >> 5;
  for (int i = tid; i < 1024; i += 256) { ((int*)acc)[i] = 0; ((int*)cnt)[i] = 0; }
  __syncthreads();

  float scale = (float)scale_p[0];
  float lin0 = lin[0];
  float step = (lin[31] - lin0) * (1.f / 31.f);
  float istep = 1.f / step;
  float Cl = scale * step * 1.44269504088896f;  // log2-slope per bin
  float w = 25.f / (scale * step);              // transition half-width (bins)

#pragma unroll 2
  for (int idx = srow; idx < nrem; idx += 8) {
    int m = sorted[start + idx];
    float h;
    int isn;
    if (m < N) {
      h = nh[(size_t)m * 32 + t];
      isn = 1;
    } else if (m < N + E) {
      int e = m - N;
      h = fmaxf(nh[(size_t)ei[e] * 32 + t], nh[(size_t)ei[E + e] * 32 + t]);
      isn = -1;
    } else {
      int f = m - N - E;
      h = fmaxf(fmaxf(nh[(size_t)face[f] * 32 + t],
                      nh[(size_t)face[F + f] * 32 + t]),
                nh[(size_t)face[2 * F + f] * 32 + t]);
      isn = 1;
    }
    float kf = (h - lin0) * istep;
    int b0 = (int)ceilf(kf - w);
    int b1 = (int)floorf(kf + w);
    int fs = max(b1 + 1, 0);
    if (fs <= 31) atomicAdd(&cnt[fs][t], isn);
    float q = Cl * kf;
    float fsn = (float)isn;
    int blo = max(b0, 0), bhi = min(b1, 31);
    for (int b = blo; b <= bhi; ++b) {
      float e2 = __builtin_amdgcn_exp2f(fmaf(-Cl, (float)b, q));
      float val = fsn * __builtin_amdgcn_rcpf(1.f + e2);
      atomicAdd(&acc[b][t], (int)rintf(val * 1048576.f));
    }
  }
  __syncthreads();
  if (tid < 32) {  // prefix-sum cnt over bins for theta=tid
    int run = 0;
    for (int k = 0; k < 32; ++k) { run += cnt[k][tid]; cnt[k][tid] = run; }
  }
  __syncthreads();
  for (int i = tid; i < 1024; i += 256) {
    int b = i >> 5, tt = i & 31;
    partial[(size_t)bid * 1024 + i] =
        (float)cnt[b][tt] + (float)acc[b][tt] * (1.f / 1048576.f);
  }
}

// K5: tree-reduction stage 1. Block = (graph g, slice s): sums chunks
// c = s, s+RS, ... into partial2[(g*RS+s)*1024 + cell].
__global__ __launch_bounds__(256) void reduce_kernel(
    const float* __restrict__ partial, const int* __restrict__ meta,
    float* __restrict__ partial2) {
  int g = blockIdx.x >> 4, s = blockIdx.x & (RS - 1);
  int tid = threadIdx.x;
  int nch = (meta[g] + CHUNK - 1) / CHUNK;
  int pbase = meta[16 + g];
  float a0 = 0.f, a1 = 0.f, a2 = 0.f, a3 = 0.f;
  for (int c = s; c < nch; c += RS) {
    const float* p = partial + (size_t)(pbase + c) * 1024;
    a0 += p[tid];
    a1 += p[tid + 256];
    a2 += p[tid + 512];
    a3 += p[tid + 768];
  }
  float* q = partial2 + (size_t)blockIdx.x * 1024;
  q[tid] = a0;
  q[tid + 256] = a1;
  q[tid + 512] = a2;
  q[tid + 768] = a3;
}

// K6: sum RS slices per cell, per-graph max, normalize
__global__ __launch_bounds__(1024) void fin_kernel(const float* __restrict__ partial2,
    float* __restrict__ out) {
  int g = blockIdx.x, tid = threadIdx.x;
  float acc = 0.f;
#pragma unroll
  for (int s = 0; s < RS; ++s)
    acc += partial2[(size_t)(g * RS + s) * 1024 + tid];
  float m = acc;
#pragma unroll
  for (int off = 32; off > 0; off >>= 1) m = fmaxf(m, __shfl_down(m, off));
  __shared__ float wmax[16];
  if ((tid & 63) == 0) wmax[tid >> 6] = m;
  __syncthreads();
  if (tid == 0) {
    float mm = wmax[0];
#pragma unroll
    for (int ww = 1; ww < 16; ++ww) mm = fmaxf(mm, wmax[ww]);
    wmax[0] = mm;
  }
  __syncthreads();
  out[(size_t)g * 1024 + tid] = acc / wmax[0];
}

extern "C" void kernel_launch(void* const* d_in, const int* in_sizes, int n_in,
                              void* d_out, int out_size, void* d_ws, size_t ws_size,
                              hipStream_t stream) {
  const float* x     = (const float*)d_in[0];
  const float* v     = (const float*)d_in[1];
  const float* lin   = (const float*)d_in[2];
  const int*   ei    = (const int*)d_in[3];
  const int*   face  = (const int*)d_in[4];
  const int*   batch = (const int*)d_in[5];
  const int*   scale = (const int*)d_in[6];
  const int N = in_sizes[5];
  const int E = in_sizes[3] / 2;
  const int F = in_sizes[4] / 3;
  const int M = N + E + F;
  const int NB = (M + 255) / 256;

  float* nh       = (float*)d_ws;                 // N*32 f32
  int*   sorted   = (int*)(nh + (size_t)N * 32);  // M
  int*   bhist    = sorted + M;                   // NB*8
  int*   base     = bhist + (size_t)NB * 8;       // NB*8
  int*   meta     = base + (size_t)NB * 8;        // 32
  float* partial  = (float*)(meta + 32);          // (M/CHUNK+8)*1024 f32
  float* partial2 = partial + (size_t)((M + CHUNK - 1) / CHUNK + 8) * 1024;  // 8*RS*1024

  int grid1 = max((N * 32 + 255) / 256, NB);
  nh_count_kernel<<<grid1, 256, 0, stream>>>(x, v, nh, ei, face, batch, bhist,
                                             N, E, F, NB);
  scan_kernel<<<1, 256, 0, stream>>>(bhist, base, meta, NB);
  scatter_kernel<<<NB, 256, 0, stream>>>(ei, face, batch, base, sorted, N, E, F);
  const int grid_ect = (M + CHUNK - 1) / CHUNK + 8;
  ect_kernel<<<grid_ect, 256, 0, stream>>>(nh, ei, face, sorted, meta, lin,
                                           scale, partial, N, E, F);
  reduce_kernel<<<8 * RS, 256, 0, stream>>>(partial, meta, partial2);
  fin_kernel<<<8, 1024, 0, stream>>>(partial2, (float*)d_out);
}